// Round 11
// baseline (108.964 us; speedup 1.0000x reference)
//
#include <hip/hip_runtime.h>

// Inclusive prefix-sum along L of X[B=8][L=4096][D=64][N=16] fp32.
// Single-pass, zero global sync: block owns one (b, 128-byte dn-slice) for all
// of L, processed in 4 sequential segments of 1024 rows. Per segment:
// 8-row serial scan in regs -> shfl scan over 8 row-groups per wave ->
// 16 wave-aggregates to LDS -> ONE nodrain barrier -> broadcast-sum offsets.
// Next segment prefetched into regs; raw s_barrier keeps loads in flight.
// Round-11 change: bare __launch_bounds__(1024) -- the ",4" min-waves hint
// made the compiler cap at 64 VGPR (2048/32-wave target) and spill the
// payload (round-10 WRITE_SIZE 230 MB = 134 + ~96 MB spill).

typedef float f4 __attribute__((ext_vector_type(4)));

constexpr int BB   = 8;
constexpr int LL   = 4096;
constexpr int DN   = 1024;          // D*N floats, contiguous per (b,l)
constexpr int COLS = 8;             // f4 columns per block = 128 B slice
constexpr int NSL  = DN / (COLS * 4);  // 32 slices per batch
constexpr int TPB  = 1024;          // 16 waves
constexpr int G    = TPB / COLS;    // 128 row-groups
constexpr int NSEG = 4;
constexpr int SEGR = LL / NSEG;     // 1024 rows per segment
constexpr int R    = SEGR / G;      // 8 rows per thread per segment
constexpr int NW   = TPB / 64;      // 16 waves

__device__ __forceinline__ void barrier_nodrain() {
    // LDS writes must land before the barrier; global loads stay in flight.
    asm volatile("s_waitcnt lgkmcnt(0)" ::: "memory");
    __builtin_amdgcn_s_barrier();
}

__device__ __forceinline__ f4 shfl_up8(f4 v, int delta) {
    f4 r;
    r.x = __shfl_up(v.x, delta, 64);
    r.y = __shfl_up(v.y, delta, 64);
    r.z = __shfl_up(v.z, delta, 64);
    r.w = __shfl_up(v.w, delta, 64);
    return r;
}

__global__ __launch_bounds__(TPB) void scan_seg(const float* __restrict__ x,
                                                float* __restrict__ out) {
    __shared__ f4 wagg[2][NW][COLS];     // 4 KB, double-buffered by seg parity

    const int bid = blockIdx.x;          // b*NSL + s
    const int b = bid >> 5, s = bid & (NSL - 1);
    const int t = threadIdx.x;
    const int dn4 = t & (COLS - 1);      // f4 column within slice
    const int g   = t >> 3;              // row-group [0,128)
    const int gl  = g & 7;               // row-group within wave
    const int w   = t >> 6;              // wave [0,16)

    const size_t colbase = (size_t)b * LL * DN + (size_t)s * (COLS * 4);
    const f4* xp = reinterpret_cast<const f4*>(x + colbase) + dn4;
    f4* op = reinterpret_cast<f4*>(out + colbase) + dn4;
    const int row0 = g * R;              // row offset within segment

    f4 cur[R], nxt[R];
    #pragma unroll
    for (int i = 0; i < R; ++i) cur[i] = xp[(size_t)(row0 + i) * (DN / 4)];

    f4 carry = (f4)0.f;
    #pragma unroll
    for (int sg = 0; sg < NSEG; ++sg) {
        // Prefetch next segment; loads remain outstanding across the barrier.
        if (sg + 1 < NSEG) {
            const size_t rb = (size_t)((sg + 1) * SEGR + row0);
            #pragma unroll
            for (int i = 0; i < R; ++i) nxt[i] = xp[(rb + i) * (DN / 4)];
        }
        // Serial inclusive scan of this thread's 8 rows.
        f4 run = (f4)0.f;
        #pragma unroll
        for (int i = 0; i < R; ++i) { run += cur[i]; cur[i] = run; }
        // Wave-level scan of the 8 row-group aggregates (same dn4 lanes).
        f4 r = run;
        #pragma unroll
        for (int k = 1; k < 8; k <<= 1) {
            f4 u = shfl_up8(r, k * 8);
            if (gl >= k) r += u;
        }
        if (gl == 7) wagg[sg & 1][w][dn4] = r;   // wave aggregate
        barrier_nodrain();
        // Broadcast-read all 16 wave aggregates: prefix for w'<w, total for carry.
        f4 woff = (f4)0.f, tot = (f4)0.f;
        #pragma unroll
        for (int ww = 0; ww < NW; ++ww) {
            f4 a = wagg[sg & 1][ww][dn4];
            tot += a;
            if (ww < w) woff += a;
        }
        const f4 off = carry + woff + (r - run);   // r-run = excl within wave
        const size_t ob = (size_t)(sg * SEGR + row0);
        #pragma unroll
        for (int i = 0; i < R; ++i) op[(ob + i) * (DN / 4)] = cur[i] + off;
        carry += tot;
        if (sg + 1 < NSEG) {
            #pragma unroll
            for (int i = 0; i < R; ++i) cur[i] = nxt[i];
        }
    }
}

extern "C" void kernel_launch(void* const* d_in, const int* in_sizes, int n_in,
                              void* d_out, int out_size, void* d_ws, size_t ws_size,
                              hipStream_t stream) {
    const float* x = (const float*)d_in[0];
    float* out = (float*)d_out;
    scan_seg<<<dim3(BB * NSL), dim3(TPB), 0, stream>>>(x, out);
}

// Round 12
// 70.753 us; speedup vs baseline: 1.5401x; 1.5401x over previous
//
#include <hip/hip_runtime.h>

// Inclusive prefix-sum along L of X[B=8][L=4096][D=64][N=16] fp32.
// Single-pass, zero global sync: block owns one (b, 128-byte dn-slice) for all
// of L, processed in 8 sequential segments of 512 rows. Per segment:
// 4-row serial scan in regs -> shfl scan over 8 row-groups per wave ->
// 16 wave-aggregates to LDS -> ONE nodrain barrier -> broadcast-sum offsets.
// Next segment prefetched into regs; raw s_barrier keeps loads in flight.
// Round-12 change: R 8->4 (NSEG 4->8) so payload fits the empirical 64-VGPR
// cap on 1024-thread kernels (rounds 9-11 all spilled ~96 MB at R=8).

typedef float f4 __attribute__((ext_vector_type(4)));

constexpr int BB   = 8;
constexpr int LL   = 4096;
constexpr int DN   = 1024;          // D*N floats, contiguous per (b,l)
constexpr int COLS = 8;             // f4 columns per block = 128 B slice
constexpr int NSL  = DN / (COLS * 4);  // 32 slices per batch
constexpr int TPB  = 1024;          // 16 waves
constexpr int G    = TPB / COLS;    // 128 row-groups
constexpr int NSEG = 8;
constexpr int SEGR = LL / NSEG;     // 512 rows per segment
constexpr int R    = SEGR / G;      // 4 rows per thread per segment
constexpr int NW   = TPB / 64;      // 16 waves

__device__ __forceinline__ void barrier_nodrain() {
    // LDS writes must land before the barrier; global loads stay in flight.
    asm volatile("s_waitcnt lgkmcnt(0)" ::: "memory");
    __builtin_amdgcn_s_barrier();
}

__device__ __forceinline__ f4 shfl_up8(f4 v, int delta) {
    f4 r;
    r.x = __shfl_up(v.x, delta, 64);
    r.y = __shfl_up(v.y, delta, 64);
    r.z = __shfl_up(v.z, delta, 64);
    r.w = __shfl_up(v.w, delta, 64);
    return r;
}

__global__ __launch_bounds__(TPB) void scan_seg(const float* __restrict__ x,
                                                float* __restrict__ out) {
    __shared__ f4 wagg[2][NW][COLS];     // 4 KB, double-buffered by seg parity

    const int bid = blockIdx.x;          // b*NSL + s
    const int b = bid >> 5, s = bid & (NSL - 1);
    const int t = threadIdx.x;
    const int dn4 = t & (COLS - 1);      // f4 column within slice
    const int g   = t >> 3;              // row-group [0,128)
    const int gl  = g & 7;               // row-group within wave
    const int w   = t >> 6;              // wave [0,16)

    const size_t colbase = (size_t)b * LL * DN + (size_t)s * (COLS * 4);
    const f4* xp = reinterpret_cast<const f4*>(x + colbase) + dn4;
    f4* op = reinterpret_cast<f4*>(out + colbase) + dn4;
    const int row0 = g * R;              // row offset within segment

    f4 cur[R], nxt[R];
    #pragma unroll
    for (int i = 0; i < R; ++i) cur[i] = xp[(size_t)(row0 + i) * (DN / 4)];

    f4 carry = (f4)0.f;
    #pragma unroll
    for (int sg = 0; sg < NSEG; ++sg) {
        // Prefetch next segment; loads remain outstanding across the barrier.
        if (sg + 1 < NSEG) {
            const size_t rb = (size_t)((sg + 1) * SEGR + row0);
            #pragma unroll
            for (int i = 0; i < R; ++i) nxt[i] = xp[(rb + i) * (DN / 4)];
        }
        // Serial inclusive scan of this thread's 4 rows.
        f4 run = (f4)0.f;
        #pragma unroll
        for (int i = 0; i < R; ++i) { run += cur[i]; cur[i] = run; }
        // Wave-level scan of the 8 row-group aggregates (same dn4 lanes).
        f4 r = run;
        #pragma unroll
        for (int k = 1; k < 8; k <<= 1) {
            f4 u = shfl_up8(r, k * 8);
            if (gl >= k) r += u;
        }
        if (gl == 7) wagg[sg & 1][w][dn4] = r;   // wave aggregate
        barrier_nodrain();
        // Broadcast-read all 16 wave aggregates: prefix for w'<w, total for carry.
        f4 woff = (f4)0.f, tot = (f4)0.f;
        #pragma unroll
        for (int ww = 0; ww < NW; ++ww) {
            f4 a = wagg[sg & 1][ww][dn4];
            tot += a;
            if (ww < w) woff += a;
        }
        const f4 off = carry + woff + (r - run);   // r-run = excl within wave
        const size_t ob = (size_t)(sg * SEGR + row0);
        #pragma unroll
        for (int i = 0; i < R; ++i) op[(ob + i) * (DN / 4)] = cur[i] + off;
        carry += tot;
        if (sg + 1 < NSEG) {
            #pragma unroll
            for (int i = 0; i < R; ++i) cur[i] = nxt[i];
        }
    }
}

extern "C" void kernel_launch(void* const* d_in, const int* in_sizes, int n_in,
                              void* d_out, int out_size, void* d_ws, size_t ws_size,
                              hipStream_t stream) {
    const float* x = (const float*)d_in[0];
    float* out = (float*)d_out;
    scan_seg<<<dim3(BB * NSL), dim3(TPB), 0, stream>>>(x, out);
}

// Round 13
// 46.218 us; speedup vs baseline: 2.3576x; 1.5309x over previous
//
#include <hip/hip_runtime.h>

// Inclusive prefix-sum along L of X[B=8][L=4096][D=64][N=16] fp32.
// Single-pass, zero global sync: block owns one (b, 128-byte dn-slice) for all
// of L, processed in 16 sequential segments of 256 rows. Per segment:
// 2-row serial scan in regs -> shfl scan over 8 row-groups per wave ->
// 16 wave-aggregates to LDS -> ONE nodrain barrier -> broadcast-sum offsets.
// Round-13 change: R 4->2 (NSEG 8->16). Round-12 still spilled ~20 MB
// (WRITE 151.5 vs 131 MiB ideal) under the empirical 64-VGPR cap on
// 1024-thread kernels; R=2 payload (~50 live regs) provably fits.
// A/B fork: if dur stays ~70 with clean WRITE, the column access pattern's
// DRAM locality is the ceiling, not the spill.

typedef float f4 __attribute__((ext_vector_type(4)));

constexpr int BB   = 8;
constexpr int LL   = 4096;
constexpr int DN   = 1024;          // D*N floats, contiguous per (b,l)
constexpr int COLS = 8;             // f4 columns per block = 128 B slice
constexpr int NSL  = DN / (COLS * 4);  // 32 slices per batch
constexpr int TPB  = 1024;          // 16 waves
constexpr int G    = TPB / COLS;    // 128 row-groups
constexpr int NSEG = 16;
constexpr int SEGR = LL / NSEG;     // 256 rows per segment
constexpr int R    = SEGR / G;      // 2 rows per thread per segment
constexpr int NW   = TPB / 64;      // 16 waves

__device__ __forceinline__ void barrier_nodrain() {
    // LDS writes must land before the barrier; global loads stay in flight.
    asm volatile("s_waitcnt lgkmcnt(0)" ::: "memory");
    __builtin_amdgcn_s_barrier();
}

__device__ __forceinline__ f4 shfl_up8(f4 v, int delta) {
    f4 r;
    r.x = __shfl_up(v.x, delta, 64);
    r.y = __shfl_up(v.y, delta, 64);
    r.z = __shfl_up(v.z, delta, 64);
    r.w = __shfl_up(v.w, delta, 64);
    return r;
}

__global__ __launch_bounds__(TPB) void scan_seg(const float* __restrict__ x,
                                                float* __restrict__ out) {
    __shared__ f4 wagg[2][NW][COLS];     // 4 KB, double-buffered by seg parity

    const int bid = blockIdx.x;          // b*NSL + s
    const int b = bid >> 5, s = bid & (NSL - 1);
    const int t = threadIdx.x;
    const int dn4 = t & (COLS - 1);      // f4 column within slice
    const int g   = t >> 3;              // row-group [0,128)
    const int gl  = g & 7;               // row-group within wave
    const int w   = t >> 6;              // wave [0,16)

    const size_t colbase = (size_t)b * LL * DN + (size_t)s * (COLS * 4);
    const f4* xp = reinterpret_cast<const f4*>(x + colbase) + dn4;
    f4* op = reinterpret_cast<f4*>(out + colbase) + dn4;
    const int row0 = g * R;              // row offset within segment

    f4 cur[R], nxt[R];
    #pragma unroll
    for (int i = 0; i < R; ++i) cur[i] = xp[(size_t)(row0 + i) * (DN / 4)];

    f4 carry = (f4)0.f;
    #pragma unroll
    for (int sg = 0; sg < NSEG; ++sg) {
        // Prefetch next segment; loads remain outstanding across the barrier.
        if (sg + 1 < NSEG) {
            const size_t rb = (size_t)((sg + 1) * SEGR + row0);
            #pragma unroll
            for (int i = 0; i < R; ++i) nxt[i] = xp[(rb + i) * (DN / 4)];
        }
        // Serial inclusive scan of this thread's rows.
        f4 run = (f4)0.f;
        #pragma unroll
        for (int i = 0; i < R; ++i) { run += cur[i]; cur[i] = run; }
        // Wave-level scan of the 8 row-group aggregates (same dn4 lanes).
        f4 r = run;
        #pragma unroll
        for (int k = 1; k < 8; k <<= 1) {
            f4 u = shfl_up8(r, k * 8);
            if (gl >= k) r += u;
        }
        if (gl == 7) wagg[sg & 1][w][dn4] = r;   // wave aggregate
        barrier_nodrain();
        // Broadcast-read all 16 wave aggregates: prefix for w'<w, total for carry.
        f4 woff = (f4)0.f, tot = (f4)0.f;
        #pragma unroll
        for (int ww = 0; ww < NW; ++ww) {
            f4 a = wagg[sg & 1][ww][dn4];
            tot += a;
            if (ww < w) woff += a;
        }
        const f4 off = carry + woff + (r - run);   // r-run = excl within wave
        const size_t ob = (size_t)(sg * SEGR + row0);
        #pragma unroll
        for (int i = 0; i < R; ++i) op[(ob + i) * (DN / 4)] = cur[i] + off;
        carry += tot;
        if (sg + 1 < NSEG) {
            #pragma unroll
            for (int i = 0; i < R; ++i) cur[i] = nxt[i];
        }
    }
}

extern "C" void kernel_launch(void* const* d_in, const int* in_sizes, int n_in,
                              void* d_out, int out_size, void* d_ws, size_t ws_size,
                              hipStream_t stream) {
    const float* x = (const float*)d_in[0];
    float* out = (float*)d_out;
    scan_seg<<<dim3(BB * NSL), dim3(TPB), 0, stream>>>(x, out);
}

// Round 14
// 45.401 us; speedup vs baseline: 2.4000x; 1.0180x over previous
//
#include <hip/hip_runtime.h>

// Inclusive prefix-sum along L of X[B=8][L=4096][D=64][N=16] fp32.
// Single-pass, zero global sync: block owns one (b, 128-byte dn-slice) for all
// of L, processed in 16 sequential segments of 256 rows. Per segment:
// 2-row serial scan in regs -> shfl scan over 8 row-groups per wave ->
// 16 wave-aggregates to LDS -> ONE nodrain barrier -> broadcast-sum offsets.
// R=2 payload fits the empirical 64-VGPR cap on 1024-thread kernels
// (round 13: WRITE exactly 128 MiB = no spill, 46.2 us, 5.8 TB/s).
// Round-14 single change: NONTEMPORAL output stores (write stream doesn't
// allocate in L2/L3 -> less pressure against read+prefetch streams).

typedef float f4 __attribute__((ext_vector_type(4)));

constexpr int BB   = 8;
constexpr int LL   = 4096;
constexpr int DN   = 1024;          // D*N floats, contiguous per (b,l)
constexpr int COLS = 8;             // f4 columns per block = 128 B slice
constexpr int NSL  = DN / (COLS * 4);  // 32 slices per batch
constexpr int TPB  = 1024;          // 16 waves
constexpr int G    = TPB / COLS;    // 128 row-groups
constexpr int NSEG = 16;
constexpr int SEGR = LL / NSEG;     // 256 rows per segment
constexpr int R    = SEGR / G;      // 2 rows per thread per segment
constexpr int NW   = TPB / 64;      // 16 waves

__device__ __forceinline__ void barrier_nodrain() {
    // LDS writes must land before the barrier; global loads stay in flight.
    asm volatile("s_waitcnt lgkmcnt(0)" ::: "memory");
    __builtin_amdgcn_s_barrier();
}

__device__ __forceinline__ f4 shfl_up8(f4 v, int delta) {
    f4 r;
    r.x = __shfl_up(v.x, delta, 64);
    r.y = __shfl_up(v.y, delta, 64);
    r.z = __shfl_up(v.z, delta, 64);
    r.w = __shfl_up(v.w, delta, 64);
    return r;
}

__global__ __launch_bounds__(TPB) void scan_seg(const float* __restrict__ x,
                                                float* __restrict__ out) {
    __shared__ f4 wagg[2][NW][COLS];     // 4 KB, double-buffered by seg parity

    const int bid = blockIdx.x;          // b*NSL + s
    const int b = bid >> 5, s = bid & (NSL - 1);
    const int t = threadIdx.x;
    const int dn4 = t & (COLS - 1);      // f4 column within slice
    const int g   = t >> 3;              // row-group [0,128)
    const int gl  = g & 7;               // row-group within wave
    const int w   = t >> 6;              // wave [0,16)

    const size_t colbase = (size_t)b * LL * DN + (size_t)s * (COLS * 4);
    const f4* xp = reinterpret_cast<const f4*>(x + colbase) + dn4;
    f4* op = reinterpret_cast<f4*>(out + colbase) + dn4;
    const int row0 = g * R;              // row offset within segment

    f4 cur[R], nxt[R];
    #pragma unroll
    for (int i = 0; i < R; ++i) cur[i] = xp[(size_t)(row0 + i) * (DN / 4)];

    f4 carry = (f4)0.f;
    #pragma unroll
    for (int sg = 0; sg < NSEG; ++sg) {
        // Prefetch next segment; loads remain outstanding across the barrier.
        if (sg + 1 < NSEG) {
            const size_t rb = (size_t)((sg + 1) * SEGR + row0);
            #pragma unroll
            for (int i = 0; i < R; ++i) nxt[i] = xp[(rb + i) * (DN / 4)];
        }
        // Serial inclusive scan of this thread's rows.
        f4 run = (f4)0.f;
        #pragma unroll
        for (int i = 0; i < R; ++i) { run += cur[i]; cur[i] = run; }
        // Wave-level scan of the 8 row-group aggregates (same dn4 lanes).
        f4 r = run;
        #pragma unroll
        for (int k = 1; k < 8; k <<= 1) {
            f4 u = shfl_up8(r, k * 8);
            if (gl >= k) r += u;
        }
        if (gl == 7) wagg[sg & 1][w][dn4] = r;   // wave aggregate
        barrier_nodrain();
        // Broadcast-read all 16 wave aggregates: prefix for w'<w, total for carry.
        f4 woff = (f4)0.f, tot = (f4)0.f;
        #pragma unroll
        for (int ww = 0; ww < NW; ++ww) {
            f4 a = wagg[sg & 1][ww][dn4];
            tot += a;
            if (ww < w) woff += a;
        }
        const f4 off = carry + woff + (r - run);   // r-run = excl within wave
        const size_t ob = (size_t)(sg * SEGR + row0);
        #pragma unroll
        for (int i = 0; i < R; ++i)
            __builtin_nontemporal_store(cur[i] + off, op + (ob + i) * (DN / 4));
        carry += tot;
        if (sg + 1 < NSEG) {
            #pragma unroll
            for (int i = 0; i < R; ++i) cur[i] = nxt[i];
        }
    }
}

extern "C" void kernel_launch(void* const* d_in, const int* in_sizes, int n_in,
                              void* d_out, int out_size, void* d_ws, size_t ws_size,
                              hipStream_t stream) {
    const float* x = (const float*)d_in[0];
    float* out = (float*)d_out;
    scan_seg<<<dim3(BB * NSL), dim3(TPB), 0, stream>>>(x, out);
}